// Round 9
// baseline (194.550 us; speedup 1.0000x reference)
//
#include <hip/hip_runtime.h>
#include <hip/hip_bf16.h>

// Problem constants (fixed by the reference)
#define BATCH 8
#define NPTS  4096      // N
#define CCH   128      // C
#define KNN_K 16       // K

typedef __attribute__((ext_vector_type(8))) short  bf16x8;  // 8 bf16 = 4 VGPRs
typedef __attribute__((ext_vector_type(4))) float  f32x4;   // MFMA acc
typedef __attribute__((ext_vector_type(2))) float  f32x2;   // packed-fp32 pair

// ---------------------------------------------------------------------------
// ws layout (bytes):
//   [0)        scale : C fp32         =       512
//   [512)      bias  : C fp32         =       512
//   [1024)     pts   : B*N*4 fp32 pair-SoA blocks = 524,288
//   [525312)   Zb    : B*N*C bf16     = 8,388,608   (Z = W@x, [B,N,C])
// total 8,913,920.  pts' depth-1 prefetch over-reads <=512B past pts' end,
// which lands in Zb — in-bounds of ws, values never consumed.
//
// pts pair-SoA layout (per batch, 2048 blocks of 32B):
//   block m (c=m>>4, s=m&15) holds points i0 = 32c+s and i1 = i0+16 as
//   {2*x0,2*x1, 2*y0,2*y1, 2*z0,2*z1, s0,s1}.  xyz are stored DOUBLED
//   (s raw): dot' = (qx*2px + qy*2py) + qz*2pz == 2*dot with identical
//   RNE rounding at every step (scaling by 2 is exact and commutes with
//   rounding), so d2 = (qw+pw) - dot' is bit-identical to the reference
//   (qw+pw) - (dot+dot) while saving one pk op per chunk. Queries recover
//   raw coords via exact *0.5. Slot0/slot1 reproduce the exact low16/high16
//   candidate->ballot-bit mapping of the scalar version.
// ---------------------------------------------------------------------------

static __device__ __forceinline__ short f2bf(float v) {
    __hip_bfloat16 h = __float2bfloat16(v);   // RNE
    return __builtin_bit_cast(short, h);
}

// Dense GEMM with fused transpose AND fused prep:
//   - blocks 0..63:  also convert xyz -> pair-SoA pts (one pair-block/thread)
//   - block 64:      also fold BN affine into scale/bias
//   - all blocks:    Z[g, c] = sum_k x[b, k, n] * W[c, k], Z bf16 [B*N, C]
// W staged fp32 -> bf16 (RNE) into LDS, pitch 136. Verified fragment mappings
// (A: m=lane&15, k=(lane>>4)*8+j; B: n=lane&15, same k-slice; C/D:
// col=lane&15, row=(lane>>4)*4+reg).
__global__ __launch_bounds__(256) void zgemm_prep_kernel(
    const float* __restrict__ x, const float* __restrict__ W,
    const float* __restrict__ xyz,
    const float* __restrict__ gamma, const float* __restrict__ beta,
    const float* __restrict__ rmean, const float* __restrict__ rvar,
    float* __restrict__ scale, float* __restrict__ bias,
    float* __restrict__ pts, short* __restrict__ Zb)
{
    __shared__ short sW[CCH * 136];
    const int lane = threadIdx.x & 63;
    const int wid  = threadIdx.x >> 6;
    const int kl   = lane & 15;
    const int q8   = (lane >> 4) * 8;

    // ---- fused prep slices --------------------------------------------------
    const int t = blockIdx.x * 256 + threadIdx.x;
    if (t < BATCH * NPTS / 2) {                 // blocks 0..63: pts pair-blocks
        const int b  = t >> 11;                 // 2048 blocks per batch
        const int mb = t & 2047;
        const int c  = mb >> 4, s = mb & 15;
        const int i0 = b * NPTS + 32 * c + s;   // global point indices
        const int i1 = i0 + 16;
        {
            #pragma clang fp contract(off)
            const float x0 = xyz[3 * i0 + 0], y0 = xyz[3 * i0 + 1], z0 = xyz[3 * i0 + 2];
            const float x1 = xyz[3 * i1 + 0], y1 = xyz[3 * i1 + 1], z1 = xyz[3 * i1 + 2];
            const float s0 = x0 * x0 + y0 * y0 + z0 * z0;   // matches ref s = sum(xyz*xyz)
            const float s1 = x1 * x1 + y1 * y1 + z1 * z1;
            float4* o = (float4*)(pts + (size_t)t * 8);
            o[0] = make_float4(2.0f * x0, 2.0f * x1, 2.0f * y0, 2.0f * y1);
            o[1] = make_float4(2.0f * z0, 2.0f * z1, s0, s1);
        }
    }
    if (blockIdx.x == 64 && threadIdx.x < CCH) {
        const int c = threadIdx.x;
        const float s = gamma[c] / sqrtf(rvar[c] + 1e-5f);
        scale[c] = s;
        bias[c]  = beta[c] - rmean[c] * s;
    }

    // ---- stage W: fp32 -> bf16 -> LDS (16384 elems) -------------------------
    #pragma unroll
    for (int it = 0; it < 8; ++it) {
        const int e = (it * 256 + threadIdx.x) * 8;
        const int r = e >> 7, c = e & 127;
        const float4 w0 = *(const float4*)(W + e);
        const float4 w1 = *(const float4*)(W + e + 4);
        bf16x8 wb;
        wb[0] = f2bf(w0.x); wb[1] = f2bf(w0.y); wb[2] = f2bf(w0.z); wb[3] = f2bf(w0.w);
        wb[4] = f2bf(w1.x); wb[5] = f2bf(w1.y); wb[6] = f2bf(w1.z); wb[7] = f2bf(w1.w);
        *(bf16x8*)(sW + r * 136 + c) = wb;
    }

    const int G = blockIdx.x * 64 + wid * 16 + kl;   // A-row (flat B*N)
    const int b = G >> 12, n = G & 4095;
    const float* xp = x + (size_t)b * CCH * NPTS + n;
    __syncthreads();

    const f32x4 zero = {0.f, 0.f, 0.f, 0.f};
    f32x4 acc[8];
    #pragma unroll
    for (int tt = 0; tt < 8; ++tt) acc[tt] = zero;

    #pragma unroll
    for (int kk = 0; kk < 4; ++kk) {
        bf16x8 a;
        #pragma unroll
        for (int j = 0; j < 8; ++j)
            a[j] = f2bf(xp[(size_t)(kk * 32 + q8 + j) * NPTS]);
        #pragma unroll
        for (int tt = 0; tt < 8; ++tt) {
            const bf16x8 bf = *(const bf16x8*)(sW + (tt * 16 + kl) * 136 + kk * 32 + q8);
            acc[tt] = __builtin_amdgcn_mfma_f32_16x16x32_bf16(a, bf, acc[tt], 0, 0, 0);
        }
    }

    const int rbase = blockIdx.x * 64 + wid * 16 + (lane >> 4) * 4;
    #pragma unroll
    for (int tt = 0; tt < 8; ++tt)
        #pragma unroll
        for (int r = 0; r < 4; ++r)
            Zb[(size_t)(rbase + r) * CCH + tt * 16 + kl] = f2bf(acc[tt][r]);
}

// Fused KNN + gather/BN/ReLU/max. Block = 16 points (4 waves x 4 queries).
// Phase 1 = the round-8-verified structure (single-shuffle insert), plus:
//   (a) doubled-xyz pts: one fewer pk op per chunk (bit-identical, see ws
//       layout comment);
//   (b) wave-uniform empty-chunk early-out: if no lane in the wave has a
//       survivor, skip ballots/extract/insert/tau-refresh entirely. Exactly
//       consistent: no survivors => bd unchanged => tau already current.
// Selection remains bit-identical: same ballot bits, same ascending-j ffs
// order, same strict-< insert => reference tie-break preserved exactly.
// Phase 2: neighbor rows broadcast from the group's bj registers; gather Zb
// rows, BN+ReLU+max, LDS transpose, coalesced store.
__global__ __launch_bounds__(256) void knnmax_kernel(
    const float* __restrict__ pts, const short* __restrict__ Zb,
    const float* __restrict__ scale, const float* __restrict__ bias,
    float* __restrict__ out)
{
    __shared__ float sm[16][132];
    const int lane = threadIdx.x & 63;
    const int wid  = threadIdx.x >> 6;
    const int g    = lane >> 4;                 // group (query) 0..3
    const int s    = lane & 15;                 // slot within group
    const int wq   = blockIdx.x * 16 + wid * 4; // first query of this wave
    const int b    = wq >> 12;                  // 4 queries never cross a batch
    const int i    = (wq & 4095) + g;           // this lane's query
    const float* pp = pts + ((size_t)b << 14);  // 16384 floats per batch

    // query load from pair-SoA (coords stored doubled; *0.5 is exact):
    // point i = 32c + r -> block 16c + (r&15), slot r>>4
    float qx, qy, qz, qw;
    {
        const int c  = i >> 5, r = i & 31;
        const float* qp = pp + ((size_t)(16 * c + (r & 15)) << 3) + (r >> 4);
        qx = 0.5f * qp[0]; qy = 0.5f * qp[2]; qz = 0.5f * qp[4]; qw = qp[6];
    }
    const f32x2 qx2 = {qx, qx}, qy2 = {qy, qy}, qz2 = {qz, qz}, qw2 = {qw, qw};

    float bd = 3.4e38f;                         // slot s: s-th smallest
    int   bj = 0;
    float tau = 3.4e38f;                        // group-uniform (lane copy)
    const bool sgt0 = (s > 0);

    const float* lp = pp + ((size_t)s << 3);    // this lane's block, chunk 0
    f32x4 A = *(const f32x4*)(lp);              // 2x0,2x1,2y0,2y1
    f32x4 Bv = *(const f32x4*)(lp + 4);         // 2z0,2z1,s0,s1
    #pragma unroll 2
    for (int ch = 0; ch < 128; ++ch) {
        // Prefetch next chunk's block (128 floats ahead). At ch=127 this
        // reads past this batch's pts (next batch, or Zb for b=7) —
        // in-bounds of ws, values never consumed.
        const float* np = lp + (ch + 1) * 128;
        const f32x4 An = *(const f32x4*)(np);
        const f32x4 Bn = *(const f32x4*)(np + 4);
        float d0, d1;
        {
            #pragma clang fp contract(off)
            const f32x2 px = A.xy, py = A.zw, pz = Bv.xy, pw = Bv.zw;
            const f32x2 m1 = qx2 * px;          // = 2*(qx*px) exactly
            const f32x2 m2 = qy2 * py;
            const f32x2 m3 = qz2 * pz;
            const f32x2 dot2 = (m1 + m2) + m3;  // == 2*dot, same rounding as ref
            const f32x2 sw  = qw2 + pw;         // q.w + cs, as ref
            const f32x2 d2  = sw - dot2;        // s_i + s_j - 2*dot, as ref
            d0 = d2.x;                          // cand 32ch + s      (low 16)
            d1 = d2.y;                          // cand 32ch + s + 16 (high 16)
        }
        // Wave-uniform early-out: skip all selection machinery when no lane
        // in the wave has a survivor (common in late chunks).
        if (__any(fminf(d0, d1) < tau)) {
            const unsigned long long m0 = __ballot(d0 < tau);
            const unsigned long long m1b = __ballot(d1 < tau);
            unsigned sub = (unsigned)((m0 >> (g << 4)) & 0xFFFFull)
                         | ((unsigned)((m1b >> (g << 4)) & 0xFFFFull) << 16);
            while (__any(sub != 0)) {
                const bool has = (sub != 0);
                const int  l   = __ffs(sub) - 1;       // 0..31 (-1 if empty; unused)
                // l is group-uniform: SOURCE lane pre-selects d0/d1 -> one shuffle.
                const float dsrc = (l & 16) ? d1 : d0;
                const float dvr  = __shfl(dsrc, l & 15, 16);
                const float dv   = has ? dvr : 3.4e38f;
                const int   jv   = (ch << 5) + l;
                sub &= sub - 1;                        // 0 stays 0
                // sorted insert across the group's 16 lanes (ascending)
                const float pd = __shfl_up(bd, 1, 16);
                const int   pj = __shfl_up(bj, 1, 16);
                const bool lt  = dv < bd;
                const bool ltp = sgt0 && (dv < pd);
                bd = lt ? (ltp ? pd : dv) : bd;
                bj = lt ? (ltp ? pj : jv) : bj;
            }
            tau = __shfl(bd, 15, 16);           // refresh list max (group-uniform)
        }
        A = An; Bv = Bn;
    }

    // ---------------- phase 2: gather + BN + ReLU + max ---------------------
    // Wave handles its own 4 points; lane l covers channels 2l, 2l+1 (one
    // dword per Z-row read; full 256B row per wave, coalesced). Neighbor row
    // indices come from the wave's bj registers (group p, slot k -> lane
    // p*16+k). The gather's memory latency interleaves with OTHER waves'
    // phase-1 VALU work on the same SIMD.
    const float sc0 = scale[2 * lane], sc1 = scale[2 * lane + 1];
    const float bi0 = bias[2 * lane],  bi1 = bias[2 * lane + 1];
    const short* Zrow = Zb + ((size_t)b * NPTS) * CCH;

    for (int p = 0; p < 4; ++p) {
        float mx0 = 0.f, mx1 = 0.f;             // relu floor
        #pragma unroll
        for (int k = 0; k < 16; ++k) {
            const int r = __shfl(bj, (p << 4) + k, 64);    // within-batch row
            const unsigned v = *(const unsigned*)(Zrow + (size_t)r * CCH + 2 * lane);
            const float z0 = __uint_as_float(v << 16);
            const float z1 = __uint_as_float(v & 0xFFFF0000u);
            mx0 = fmaxf(mx0, sc0 * z0 + bi0);
            mx1 = fmaxf(mx1, sc1 * z1 + bi1);
        }
        sm[wid * 4 + p][2 * lane]     = mx0;
        sm[wid * 4 + p][2 * lane + 1] = mx1;
    }
    __syncthreads();

    const int c    = threadIdx.x & 127;
    const int half = threadIdx.x >> 7;
    float v[8];
    #pragma unroll
    for (int k = 0; k < 8; ++k) v[k] = sm[half * 8 + k][c];
    float4 f0 = {v[0], v[1], v[2], v[3]};
    float4 f1 = {v[4], v[5], v[6], v[7]};
    const int n0 = blockIdx.x * 16;             // flat point base (B*N)
    float* op = out + ((size_t)(b * CCH + c)) * NPTS + (n0 & 4095) + half * 8;
    *(float4*)op       = f0;
    *(float4*)(op + 4) = f1;
}

extern "C" void kernel_launch(void* const* d_in, const int* in_sizes, int n_in,
                              void* d_out, int out_size, void* d_ws, size_t ws_size,
                              hipStream_t stream)
{
    const float* xyz   = (const float*)d_in[0];
    const float* x     = (const float*)d_in[1];
    const float* W     = (const float*)d_in[2];
    const float* gamma = (const float*)d_in[3];
    const float* beta  = (const float*)d_in[4];
    const float* rmean = (const float*)d_in[5];
    const float* rvar  = (const float*)d_in[6];
    float* out = (float*)d_out;

    char* ws = (char*)d_ws;
    float* scale = (float*)(ws);
    float* bias  = (float*)(ws + 512);
    float* pts   = (float*)(ws + 1024);
    short* Zb    = (short*)(ws + 525312);

    zgemm_prep_kernel<<<BATCH * NPTS / 64, 256, 0, stream>>>(
        x, W, xyz, gamma, beta, rmean, rvar, scale, bias, pts, Zb);
    knnmax_kernel<<<BATCH * NPTS / 16, 256, 0, stream>>>(pts, Zb, scale, bias, out);
}

// Round 10
// 181.900 us; speedup vs baseline: 1.0695x; 1.0695x over previous
//
#include <hip/hip_runtime.h>
#include <hip/hip_bf16.h>

// Problem constants (fixed by the reference)
#define BATCH 8
#define NPTS  4096      // N
#define CCH   128      // C
#define KNN_K 16       // K

typedef __attribute__((ext_vector_type(8))) short  bf16x8;  // 8 bf16 = 4 VGPRs
typedef __attribute__((ext_vector_type(4))) float  f32x4;   // MFMA acc
typedef __attribute__((ext_vector_type(2))) float  f32x2;   // packed-fp32 pair

// ---------------------------------------------------------------------------
// ws layout (bytes):
//   [0)        scale : C fp32         =       512
//   [512)      bias  : C fp32         =       512
//   [1024)     pts   : B*N*4 fp32 pair-SoA blocks = 524,288
//   [525312)   Zb    : B*N*C bf16     = 8,388,608   (Z = W@x, [B,N,C])
// total 8,913,920.  pts' depth-1 prefetch over-reads <=512B past pts' end,
// which lands in Zb — in-bounds of ws, values never consumed.
//
// pts pair-SoA layout (per batch, 2048 blocks of 32B):
//   block m (c=m>>4, s=m&15) holds points i0 = 32c+s and i1 = i0+16 as
//   {2*x0,2*x1, 2*y0,2*y1, 2*z0,2*z1, s0,s1}.  xyz are stored DOUBLED
//   (s raw): dot' = (qx*2px + qy*2py) + qz*2pz == 2*dot with identical RNE
//   rounding at every step (scaling by 2 is exact and commutes with
//   rounding), so d2 = (qw+pw) - dot' is bit-identical to the reference
//   (qw+pw) - (dot+dot) while saving one pk op per chunk. Queries recover
//   raw coords via exact *0.5. Slot0/slot1 reproduce the exact low16/high16
//   candidate->ballot-bit mapping of the scalar version.
// ---------------------------------------------------------------------------

static __device__ __forceinline__ short f2bf(float v) {
    __hip_bfloat16 h = __float2bfloat16(v);   // RNE
    return __builtin_bit_cast(short, h);
}

// Dense GEMM with fused transpose AND fused prep:
//   - blocks 0..63:  also convert xyz -> pair-SoA pts (one pair-block/thread)
//   - block 64:      also fold BN affine into scale/bias
//   - all blocks:    Z[g, c] = sum_k x[b, k, n] * W[c, k], Z bf16 [B*N, C]
// W staged fp32 -> bf16 (RNE) into LDS, pitch 136. Verified fragment mappings
// (A: m=lane&15, k=(lane>>4)*8+j; B: n=lane&15, same k-slice; C/D:
// col=lane&15, row=(lane>>4)*4+reg).
__global__ __launch_bounds__(256) void zgemm_prep_kernel(
    const float* __restrict__ x, const float* __restrict__ W,
    const float* __restrict__ xyz,
    const float* __restrict__ gamma, const float* __restrict__ beta,
    const float* __restrict__ rmean, const float* __restrict__ rvar,
    float* __restrict__ scale, float* __restrict__ bias,
    float* __restrict__ pts, short* __restrict__ Zb)
{
    __shared__ short sW[CCH * 136];
    const int lane = threadIdx.x & 63;
    const int wid  = threadIdx.x >> 6;
    const int kl   = lane & 15;
    const int q8   = (lane >> 4) * 8;

    // ---- fused prep slices --------------------------------------------------
    const int t = blockIdx.x * 256 + threadIdx.x;
    if (t < BATCH * NPTS / 2) {                 // blocks 0..63: pts pair-blocks
        const int b  = t >> 11;                 // 2048 blocks per batch
        const int mb = t & 2047;
        const int c  = mb >> 4, s = mb & 15;
        const int i0 = b * NPTS + 32 * c + s;   // global point indices
        const int i1 = i0 + 16;
        {
            #pragma clang fp contract(off)
            const float x0 = xyz[3 * i0 + 0], y0 = xyz[3 * i0 + 1], z0 = xyz[3 * i0 + 2];
            const float x1 = xyz[3 * i1 + 0], y1 = xyz[3 * i1 + 1], z1 = xyz[3 * i1 + 2];
            const float s0 = x0 * x0 + y0 * y0 + z0 * z0;   // matches ref s = sum(xyz*xyz)
            const float s1 = x1 * x1 + y1 * y1 + z1 * z1;
            float4* o = (float4*)(pts + (size_t)t * 8);
            o[0] = make_float4(2.0f * x0, 2.0f * x1, 2.0f * y0, 2.0f * y1);
            o[1] = make_float4(2.0f * z0, 2.0f * z1, s0, s1);
        }
    }
    if (blockIdx.x == 64 && threadIdx.x < CCH) {
        const int c = threadIdx.x;
        const float s = gamma[c] / sqrtf(rvar[c] + 1e-5f);
        scale[c] = s;
        bias[c]  = beta[c] - rmean[c] * s;
    }

    // ---- stage W: fp32 -> bf16 -> LDS (16384 elems) -------------------------
    #pragma unroll
    for (int it = 0; it < 8; ++it) {
        const int e = (it * 256 + threadIdx.x) * 8;
        const int r = e >> 7, c = e & 127;
        const float4 w0 = *(const float4*)(W + e);
        const float4 w1 = *(const float4*)(W + e + 4);
        bf16x8 wb;
        wb[0] = f2bf(w0.x); wb[1] = f2bf(w0.y); wb[2] = f2bf(w0.z); wb[3] = f2bf(w0.w);
        wb[4] = f2bf(w1.x); wb[5] = f2bf(w1.y); wb[6] = f2bf(w1.z); wb[7] = f2bf(w1.w);
        *(bf16x8*)(sW + r * 136 + c) = wb;
    }

    const int G = blockIdx.x * 64 + wid * 16 + kl;   // A-row (flat B*N)
    const int b = G >> 12, n = G & 4095;
    const float* xp = x + (size_t)b * CCH * NPTS + n;
    __syncthreads();

    const f32x4 zero = {0.f, 0.f, 0.f, 0.f};
    f32x4 acc[8];
    #pragma unroll
    for (int tt = 0; tt < 8; ++tt) acc[tt] = zero;

    #pragma unroll
    for (int kk = 0; kk < 4; ++kk) {
        bf16x8 a;
        #pragma unroll
        for (int j = 0; j < 8; ++j)
            a[j] = f2bf(xp[(size_t)(kk * 32 + q8 + j) * NPTS]);
        #pragma unroll
        for (int tt = 0; tt < 8; ++tt) {
            const bf16x8 bf = *(const bf16x8*)(sW + (tt * 16 + kl) * 136 + kk * 32 + q8);
            acc[tt] = __builtin_amdgcn_mfma_f32_16x16x32_bf16(a, bf, acc[tt], 0, 0, 0);
        }
    }

    const int rbase = blockIdx.x * 64 + wid * 16 + (lane >> 4) * 4;
    #pragma unroll
    for (int tt = 0; tt < 8; ++tt)
        #pragma unroll
        for (int r = 0; r < 4; ++r)
            Zb[(size_t)(rbase + r) * CCH + tt * 16 + kl] = f2bf(acc[tt][r]);
}

// Fused KNN + gather/BN/ReLU/max. Block = 16 points (4 waves x 4 queries).
// Phase 1 = the round-8-verified structure EXACTLY (unconditional ballot
// path — R9's wave-uniform early-out branch regressed 10 µs by breaking the
// compiler's cross-iteration schedule; single-shuffle insert), with only the
// doubled-xyz folding kept from R9 (one fewer pk op per chunk, bit-identical
// — see ws layout comment). Selection remains bit-identical: same ballot
// bits, same ascending-j ffs order, same strict-< insert => reference
// tie-break preserved exactly.
// Phase 2: neighbor rows broadcast from the group's bj registers; gather Zb
// rows, BN+ReLU+max, LDS transpose, coalesced store.
__global__ __launch_bounds__(256) void knnmax_kernel(
    const float* __restrict__ pts, const short* __restrict__ Zb,
    const float* __restrict__ scale, const float* __restrict__ bias,
    float* __restrict__ out)
{
    __shared__ float sm[16][132];
    const int lane = threadIdx.x & 63;
    const int wid  = threadIdx.x >> 6;
    const int g    = lane >> 4;                 // group (query) 0..3
    const int s    = lane & 15;                 // slot within group
    const int wq   = blockIdx.x * 16 + wid * 4; // first query of this wave
    const int b    = wq >> 12;                  // 4 queries never cross a batch
    const int i    = (wq & 4095) + g;           // this lane's query
    const float* pp = pts + ((size_t)b << 14);  // 16384 floats per batch

    // query load from pair-SoA (coords stored doubled; *0.5 is exact):
    // point i = 32c + r -> block 16c + (r&15), slot r>>4
    float qx, qy, qz, qw;
    {
        const int c  = i >> 5, r = i & 31;
        const float* qp = pp + ((size_t)(16 * c + (r & 15)) << 3) + (r >> 4);
        qx = 0.5f * qp[0]; qy = 0.5f * qp[2]; qz = 0.5f * qp[4]; qw = qp[6];
    }
    const f32x2 qx2 = {qx, qx}, qy2 = {qy, qy}, qz2 = {qz, qz}, qw2 = {qw, qw};

    float bd = 3.4e38f;                         // slot s: s-th smallest
    int   bj = 0;
    float tau = 3.4e38f;                        // group-uniform (lane copy)
    const bool sgt0 = (s > 0);

    const float* lp = pp + ((size_t)s << 3);    // this lane's block, chunk 0
    f32x4 A = *(const f32x4*)(lp);              // 2x0,2x1,2y0,2y1
    f32x4 Bv = *(const f32x4*)(lp + 4);         // 2z0,2z1,s0,s1
    #pragma unroll 2
    for (int ch = 0; ch < 128; ++ch) {
        // Prefetch next chunk's block (128 floats ahead). At ch=127 this
        // reads past this batch's pts (next batch, or Zb for b=7) —
        // in-bounds of ws, values never consumed.
        const float* np = lp + (ch + 1) * 128;
        const f32x4 An = *(const f32x4*)(np);
        const f32x4 Bn = *(const f32x4*)(np + 4);
        float d0, d1;
        {
            #pragma clang fp contract(off)
            const f32x2 px = A.xy, py = A.zw, pz = Bv.xy, pw = Bv.zw;
            const f32x2 m1 = qx2 * px;          // = 2*(qx*px) exactly
            const f32x2 m2 = qy2 * py;
            const f32x2 m3 = qz2 * pz;
            const f32x2 dot2 = (m1 + m2) + m3;  // == 2*dot, same rounding as ref
            const f32x2 sw  = qw2 + pw;         // q.w + cs, as ref
            const f32x2 d2  = sw - dot2;        // s_i + s_j - 2*dot, as ref
            d0 = d2.x;                          // cand 32ch + s      (low 16)
            d1 = d2.y;                          // cand 32ch + s + 16 (high 16)
        }
        const unsigned long long m0 = __ballot(d0 < tau);
        const unsigned long long m1b = __ballot(d1 < tau);
        unsigned sub = (unsigned)((m0 >> (g << 4)) & 0xFFFFull)
                     | ((unsigned)((m1b >> (g << 4)) & 0xFFFFull) << 16);
        while (__any(sub != 0)) {
            const bool has = (sub != 0);
            const int  l   = __ffs(sub) - 1;           // 0..31 (-1 if empty; unused)
            // l is group-uniform: SOURCE lane pre-selects d0/d1 -> one shuffle.
            const float dsrc = (l & 16) ? d1 : d0;
            const float dvr  = __shfl(dsrc, l & 15, 16);
            const float dv   = has ? dvr : 3.4e38f;
            const int   jv   = (ch << 5) + l;
            sub &= sub - 1;                            // 0 stays 0
            // sorted insert across the group's 16 lanes (ascending)
            const float pd = __shfl_up(bd, 1, 16);
            const int   pj = __shfl_up(bj, 1, 16);
            const bool lt  = dv < bd;
            const bool ltp = sgt0 && (dv < pd);
            bd = lt ? (ltp ? pd : dv) : bd;
            bj = lt ? (ltp ? pj : jv) : bj;
        }
        tau = __shfl(bd, 15, 16);               // once per 32 candidates
        A = An; Bv = Bn;
    }

    // ---------------- phase 2: gather + BN + ReLU + max ---------------------
    // Wave handles its own 4 points; lane l covers channels 2l, 2l+1 (one
    // dword per Z-row read; full 256B row per wave, coalesced). Neighbor row
    // indices come from the wave's bj registers (group p, slot k -> lane
    // p*16+k). The gather's memory latency interleaves with OTHER waves'
    // phase-1 VALU work on the same SIMD.
    const float sc0 = scale[2 * lane], sc1 = scale[2 * lane + 1];
    const float bi0 = bias[2 * lane],  bi1 = bias[2 * lane + 1];
    const short* Zrow = Zb + ((size_t)b * NPTS) * CCH;

    for (int p = 0; p < 4; ++p) {
        float mx0 = 0.f, mx1 = 0.f;             // relu floor
        #pragma unroll
        for (int k = 0; k < 16; ++k) {
            const int r = __shfl(bj, (p << 4) + k, 64);    // within-batch row
            const unsigned v = *(const unsigned*)(Zrow + (size_t)r * CCH + 2 * lane);
            const float z0 = __uint_as_float(v << 16);
            const float z1 = __uint_as_float(v & 0xFFFF0000u);
            mx0 = fmaxf(mx0, sc0 * z0 + bi0);
            mx1 = fmaxf(mx1, sc1 * z1 + bi1);
        }
        sm[wid * 4 + p][2 * lane]     = mx0;
        sm[wid * 4 + p][2 * lane + 1] = mx1;
    }
    __syncthreads();

    const int c    = threadIdx.x & 127;
    const int half = threadIdx.x >> 7;
    float v[8];
    #pragma unroll
    for (int k = 0; k < 8; ++k) v[k] = sm[half * 8 + k][c];
    float4 f0 = {v[0], v[1], v[2], v[3]};
    float4 f1 = {v[4], v[5], v[6], v[7]};
    const int n0 = blockIdx.x * 16;             // flat point base (B*N)
    float* op = out + ((size_t)(b * CCH + c)) * NPTS + (n0 & 4095) + half * 8;
    *(float4*)op       = f0;
    *(float4*)(op + 4) = f1;
}

extern "C" void kernel_launch(void* const* d_in, const int* in_sizes, int n_in,
                              void* d_out, int out_size, void* d_ws, size_t ws_size,
                              hipStream_t stream)
{
    const float* xyz   = (const float*)d_in[0];
    const float* x     = (const float*)d_in[1];
    const float* W     = (const float*)d_in[2];
    const float* gamma = (const float*)d_in[3];
    const float* beta  = (const float*)d_in[4];
    const float* rmean = (const float*)d_in[5];
    const float* rvar  = (const float*)d_in[6];
    float* out = (float*)d_out;

    char* ws = (char*)d_ws;
    float* scale = (float*)(ws);
    float* bias  = (float*)(ws + 512);
    float* pts   = (float*)(ws + 1024);
    short* Zb    = (short*)(ws + 525312);

    zgemm_prep_kernel<<<BATCH * NPTS / 64, 256, 0, stream>>>(
        x, W, xyz, gamma, beta, rmean, rvar, scale, bias, pts, Zb);
    knnmax_kernel<<<BATCH * NPTS / 16, 256, 0, stream>>>(pts, Zb, scale, bias, out);
}